// Round 6
// baseline (185.372 us; speedup 1.0000x reference)
//
#include <hip/hip_runtime.h>

// LNCC loss: I,J [16,1,768,768] f32 -> out [16] f32
// Thread-autonomous design: each thread owns 4 adjacent output columns and
// redundantly computes all 12 colsums it needs (4 own + 4 halo each side).
// NO shuffles, NO LDS, NO barriers, NO register ring: the vertical 9-row
// slide re-loads the outgoing row (L3-warm; inputs fit in the 256MB L3).
// All loads are aligned float4; edges handled by clamp-address + mask-mul.
// R5->R6: SEG 16->8, WPB 3->4 (4608 waves, ~4 waves/SIMD vs 0.94) to fix the
// 11.8% occupancy latency stall; unroll 2 for cross-row load/VALU overlap.

constexpr int BATCH = 16;
constexpr int H = 768;
constexpr int W = 768;
constexpr float INV_WS = 1.0f / 81.0f;
constexpr float EPS = 3.0590232050182579e-07f;   // exp(-15)

constexpr int COLS = 4;                    // output cols per thread
constexpr int STRIPW = 64 * COLS;          // 256 cols per wave
constexpr int NSTRIP = W / STRIPW;         // 3
constexpr int SEG = 8;                     // output rows per wave task
constexpr int NSEG = H / SEG;              // 96
constexpr int WPB = 4;                     // waves per block
constexpr int NTHREADS = WPB * 64;         // 256
constexpr int BLOCKS_PER_IMG = (NSTRIP * NSEG) / WPB;   // 72

__global__ void zero_acc_kernel(float* acc) {
    if (threadIdx.x < BATCH) acc[threadIdx.x] = 0.0f;
}

__launch_bounds__(NTHREADS, 4)
__global__ void lncc4(const float* __restrict__ gI, const float* __restrict__ gJ,
                      float* __restrict__ acc)
{
    const int lane  = threadIdx.x & 63;
    const int wv    = blockIdx.x * WPB + (threadIdx.x >> 6);  // 0..287 in image
    const int b     = blockIdx.y;
    const int strip = wv % NSTRIP;
    const int seg   = wv / NSTRIP;
    const int r0    = seg * SEG;
    const int cbase = strip * STRIPW + lane * COLS;           // first owned col

    // three 16B-aligned 4-col chunks: [cbase-4], [cbase], [cbase+4]
    const float m0 = (cbase - 4 >= 0) ? 1.0f : 0.0f;   // left image edge
    const float m2 = (cbase + 8 <= W) ? 1.0f : 0.0f;   // right image edge
    const int ca0 = max(cbase - 4, 0);
    const int ca1 = cbase;
    const int ca2 = min(cbase + 4, W - 4);

    const float* __restrict__ Ib = gI + (size_t)b * (H * W);
    const float* __restrict__ Jb = gJ + (size_t)b * (H * W);

    // 8-row partial colsums of the 5 channels for the 12 columns.
    float cs0[12], cs1[12], cs2[12], cs3[12], cs4[12];
    #pragma unroll
    for (int x = 0; x < 12; ++x) {
        cs0[x] = 0.f; cs1[x] = 0.f; cs2[x] = 0.f; cs3[x] = 0.f; cs4[x] = 0.f;
    }

// 12 masked floats from one row (3 aligned float4 loads)
#define LD12(dst, base, roff, rm)                                         \
    {                                                                     \
        const float4 q0 = *(const float4*)((base) + (roff) + ca0);        \
        const float4 q1 = *(const float4*)((base) + (roff) + ca1);        \
        const float4 q2 = *(const float4*)((base) + (roff) + ca2);        \
        const float f0 = (rm) * m0, f1 = (rm), f2 = (rm) * m2;            \
        dst[0] = q0.x * f0; dst[1] = q0.y * f0;                           \
        dst[2] = q0.z * f0; dst[3] = q0.w * f0;                           \
        dst[4] = q1.x * f1; dst[5] = q1.y * f1;                           \
        dst[6] = q1.z * f1; dst[7] = q1.w * f1;                           \
        dst[8] = q2.x * f2; dst[9] = q2.y * f2;                           \
        dst[10] = q2.z * f2; dst[11] = q2.w * f2;                         \
    }

    // ---- warm-up: rows r0-4 .. r0+3 (zero above the image) ----
    #pragma unroll
    for (int k = 0; k < 8; ++k) {
        const int r = r0 - 4 + k;                 // <= 763, never >= H
        const float rm = (r >= 0) ? 1.0f : 0.0f;
        const int roff = max(r, 0) * W;
        float vi[12], vj[12];
        LD12(vi, Ib, roff, rm)
        LD12(vj, Jb, roff, rm)
        #pragma unroll
        for (int x = 0; x < 12; ++x) {
            cs0[x] += vi[x];
            cs1[x] += vj[x];
            cs2[x] = fmaf(vi[x], vi[x], cs2[x]);
            cs3[x] = fmaf(vj[x], vj[x], cs3[x]);
            cs4[x] = fmaf(vi[x], vj[x], cs4[x]);
        }
    }

    float accum = 0.0f;

    // ---- main loop: one output row per iteration (unroll 2: overlap next
    // row's independent loads with this row's dependent VALU chain) ----
    #pragma unroll 2
    for (int r = r0; r < r0 + SEG; ++r) {
        const int rin  = r + 4;                    // entering window
        const int rout = r - 4;                    // leaving window
        const float rmi = (rin < H)   ? 1.0f : 0.0f;
        const float rmo = (rout >= 0) ? 1.0f : 0.0f;
        const int oin  = min(rin, H - 1) * W;
        const int oout = max(rout, 0) * W;

        float vi[12], vj[12], oi[12], oj[12];
        LD12(vi, Ib, oin,  rmi)
        LD12(vj, Jb, oin,  rmi)
        LD12(oi, Ib, oout, rmo)
        LD12(oj, Jb, oout, rmo)

        // 9-row sums t = cs + incoming; cs <- t - outgoing (8-row for next r)
        float t0[12], t1[12], t2[12], t3[12], t4[12];
        #pragma unroll
        for (int x = 0; x < 12; ++x) {
            t0[x] = cs0[x] + vi[x];
            t1[x] = cs1[x] + vj[x];
            t2[x] = fmaf(vi[x], vi[x], cs2[x]);
            t3[x] = fmaf(vj[x], vj[x], cs3[x]);
            t4[x] = fmaf(vi[x], vj[x], cs4[x]);
            cs0[x] = t0[x] - oi[x];
            cs1[x] = t1[x] - oj[x];
            cs2[x] = fmaf(oi[x], -oi[x], t2[x]);
            cs3[x] = fmaf(oj[x], -oj[x], t3[x]);
            cs4[x] = fmaf(oi[x], -oj[x], t4[x]);
        }

        // horizontal 9-sums for the 4 owned columns (sliding within registers)
#define HSUM(T, h)                                                        \
        {                                                                 \
            float s_ = T[0] + T[1] + T[2] + T[3] + T[4] + T[5] + T[6]     \
                     + T[7] + T[8];                                       \
            h[0] = s_;                                                    \
            s_ += T[9]  - T[0]; h[1] = s_;                                \
            s_ += T[10] - T[1]; h[2] = s_;                                \
            s_ += T[11] - T[2]; h[3] = s_;                                \
        }
        float hI[4], hJ[4], hII[4], hJJ[4], hIJ[4];
        HSUM(t0, hI)
        HSUM(t1, hJ)
        HSUM(t2, hII)
        HSUM(t3, hJJ)
        HSUM(t4, hIJ)
#undef HSUM

        #pragma unroll
        for (int e = 0; e < 4; ++e) {
            const float u = -hI[e] * INV_WS;
            const float cross = fmaf(u, hJ[e], hIJ[e]);
            const float Ivar  = fmaf(u, hI[e], hII[e]);
            const float Jvar  = fmaf(-hJ[e] * INV_WS, hJ[e], hJJ[e]);
            float prod = Ivar * Jvar;
            float num  = cross * cross;
            if (!(prod > EPS)) { prod = 1.0f; num = 1.0f; }
            float inv_;
            asm("v_rcp_f32 %0, %1" : "=v"(inv_) : "v"(prod + EPS));
            accum += num * inv_;
        }
    }
#undef LD12

    // ---- wave reduction + one atomic per wave ----
    #pragma unroll
    for (int off = 32; off > 0; off >>= 1)
        accum += __shfl_xor(accum, off, 64);
    if (lane == 0) atomicAdd(&acc[b], accum);
}

__global__ void finalize_kernel(const float* __restrict__ acc, float* __restrict__ out) {
    if (threadIdx.x < BATCH)
        out[threadIdx.x] = 1.0f - acc[threadIdx.x] * (1.0f / (float)(H * W));
}

extern "C" void kernel_launch(void* const* d_in, const int* in_sizes, int n_in,
                              void* d_out, int out_size, void* d_ws, size_t ws_size,
                              hipStream_t stream) {
    const float* I = (const float*)d_in[0];
    const float* J = (const float*)d_in[1];
    float* out = (float*)d_out;
    float* acc = (float*)d_ws;

    zero_acc_kernel<<<1, 64, 0, stream>>>(acc);

    dim3 grid(BLOCKS_PER_IMG, BATCH);   // 72 x 16 = 1152 blocks, 4608 waves
    lncc4<<<grid, NTHREADS, 0, stream>>>(I, J, acc);

    finalize_kernel<<<1, 64, 0, stream>>>(acc, out);
}

// Round 7
// 86.634 us; speedup vs baseline: 2.1397x; 2.1397x over previous
//
#include <hip/hip_runtime.h>

// LNCC loss: I,J [16,1,768,768] f32 -> out [16] f32
// Thread-autonomous design: each thread owns 4 adjacent output columns and
// redundantly computes all 12 colsums it needs (4 own + 4 halo each side).
// NO shuffles, NO LDS, NO barriers, NO register ring: the vertical 9-row
// slide re-loads the outgoing row (L3-warm; inputs fit in the 256MB L3).
// All loads are aligned float4; edges handled by clamp-address + mask-mul.
// R6 post-mortem: launch_bounds(256,4)+unroll2 forced VGPR 120->64 -> 218MB
// spill traffic. R7 = exact R5 kernel (120 VGPR, no spill) + SEG 16->8 ONLY
// (4608 waves = 18/CU requested vs HW cap 16/CU at 120 VGPR).

constexpr int BATCH = 16;
constexpr int H = 768;
constexpr int W = 768;
constexpr float INV_WS = 1.0f / 81.0f;
constexpr float EPS = 3.0590232050182579e-07f;   // exp(-15)

constexpr int COLS = 4;                    // output cols per thread
constexpr int STRIPW = 64 * COLS;          // 256 cols per wave
constexpr int NSTRIP = W / STRIPW;         // 3
constexpr int SEG = 8;                     // output rows per wave task
constexpr int NSEG = H / SEG;              // 96
constexpr int WPB = 3;                     // waves per block
constexpr int NTHREADS = WPB * 64;         // 192
constexpr int BLOCKS_PER_IMG = (NSTRIP * NSEG) / WPB;   // 96

__global__ void zero_acc_kernel(float* acc) {
    if (threadIdx.x < BATCH) acc[threadIdx.x] = 0.0f;
}

__launch_bounds__(NTHREADS, 2)
__global__ void lncc4(const float* __restrict__ gI, const float* __restrict__ gJ,
                      float* __restrict__ acc)
{
    const int lane  = threadIdx.x & 63;
    const int wv    = blockIdx.x * WPB + (threadIdx.x >> 6);  // 0..287 in image
    const int b     = blockIdx.y;
    const int strip = wv % NSTRIP;
    const int seg   = wv / NSTRIP;
    const int r0    = seg * SEG;
    const int cbase = strip * STRIPW + lane * COLS;           // first owned col

    // three 16B-aligned 4-col chunks: [cbase-4], [cbase], [cbase+4]
    const float m0 = (cbase - 4 >= 0) ? 1.0f : 0.0f;   // left image edge
    const float m2 = (cbase + 8 <= W) ? 1.0f : 0.0f;   // right image edge
    const int ca0 = max(cbase - 4, 0);
    const int ca1 = cbase;
    const int ca2 = min(cbase + 4, W - 4);

    const float* __restrict__ Ib = gI + (size_t)b * (H * W);
    const float* __restrict__ Jb = gJ + (size_t)b * (H * W);

    // 8-row partial colsums of the 5 channels for the 12 columns.
    float cs0[12], cs1[12], cs2[12], cs3[12], cs4[12];
    #pragma unroll
    for (int x = 0; x < 12; ++x) {
        cs0[x] = 0.f; cs1[x] = 0.f; cs2[x] = 0.f; cs3[x] = 0.f; cs4[x] = 0.f;
    }

// 12 masked floats from one row (3 aligned float4 loads)
#define LD12(dst, base, roff, rm)                                         \
    {                                                                     \
        const float4 q0 = *(const float4*)((base) + (roff) + ca0);        \
        const float4 q1 = *(const float4*)((base) + (roff) + ca1);        \
        const float4 q2 = *(const float4*)((base) + (roff) + ca2);        \
        const float f0 = (rm) * m0, f1 = (rm), f2 = (rm) * m2;            \
        dst[0] = q0.x * f0; dst[1] = q0.y * f0;                           \
        dst[2] = q0.z * f0; dst[3] = q0.w * f0;                           \
        dst[4] = q1.x * f1; dst[5] = q1.y * f1;                           \
        dst[6] = q1.z * f1; dst[7] = q1.w * f1;                           \
        dst[8] = q2.x * f2; dst[9] = q2.y * f2;                           \
        dst[10] = q2.z * f2; dst[11] = q2.w * f2;                         \
    }

    // ---- warm-up: rows r0-4 .. r0+3 (zero above the image) ----
    #pragma unroll
    for (int k = 0; k < 8; ++k) {
        const int r = r0 - 4 + k;                 // <= 763, never >= H
        const float rm = (r >= 0) ? 1.0f : 0.0f;
        const int roff = max(r, 0) * W;
        float vi[12], vj[12];
        LD12(vi, Ib, roff, rm)
        LD12(vj, Jb, roff, rm)
        #pragma unroll
        for (int x = 0; x < 12; ++x) {
            cs0[x] += vi[x];
            cs1[x] += vj[x];
            cs2[x] = fmaf(vi[x], vi[x], cs2[x]);
            cs3[x] = fmaf(vj[x], vj[x], cs3[x]);
            cs4[x] = fmaf(vi[x], vj[x], cs4[x]);
        }
    }

    float accum = 0.0f;

    // ---- main loop: one output row per iteration ----
    #pragma unroll 1
    for (int r = r0; r < r0 + SEG; ++r) {
        const int rin  = r + 4;                    // entering window
        const int rout = r - 4;                    // leaving window
        const float rmi = (rin < H)   ? 1.0f : 0.0f;
        const float rmo = (rout >= 0) ? 1.0f : 0.0f;
        const int oin  = min(rin, H - 1) * W;
        const int oout = max(rout, 0) * W;

        float vi[12], vj[12], oi[12], oj[12];
        LD12(vi, Ib, oin,  rmi)
        LD12(vj, Jb, oin,  rmi)
        LD12(oi, Ib, oout, rmo)
        LD12(oj, Jb, oout, rmo)

        // 9-row sums t = cs + incoming; cs <- t - outgoing (8-row for next r)
        float t0[12], t1[12], t2[12], t3[12], t4[12];
        #pragma unroll
        for (int x = 0; x < 12; ++x) {
            t0[x] = cs0[x] + vi[x];
            t1[x] = cs1[x] + vj[x];
            t2[x] = fmaf(vi[x], vi[x], cs2[x]);
            t3[x] = fmaf(vj[x], vj[x], cs3[x]);
            t4[x] = fmaf(vi[x], vj[x], cs4[x]);
            cs0[x] = t0[x] - oi[x];
            cs1[x] = t1[x] - oj[x];
            cs2[x] = fmaf(oi[x], -oi[x], t2[x]);
            cs3[x] = fmaf(oj[x], -oj[x], t3[x]);
            cs4[x] = fmaf(oi[x], -oj[x], t4[x]);
        }

        // horizontal 9-sums for the 4 owned columns (sliding within registers)
#define HSUM(T, h)                                                        \
        {                                                                 \
            float s_ = T[0] + T[1] + T[2] + T[3] + T[4] + T[5] + T[6]     \
                     + T[7] + T[8];                                       \
            h[0] = s_;                                                    \
            s_ += T[9]  - T[0]; h[1] = s_;                                \
            s_ += T[10] - T[1]; h[2] = s_;                                \
            s_ += T[11] - T[2]; h[3] = s_;                                \
        }
        float hI[4], hJ[4], hII[4], hJJ[4], hIJ[4];
        HSUM(t0, hI)
        HSUM(t1, hJ)
        HSUM(t2, hII)
        HSUM(t3, hJJ)
        HSUM(t4, hIJ)
#undef HSUM

        #pragma unroll
        for (int e = 0; e < 4; ++e) {
            const float u = -hI[e] * INV_WS;
            const float cross = fmaf(u, hJ[e], hIJ[e]);
            const float Ivar  = fmaf(u, hI[e], hII[e]);
            const float Jvar  = fmaf(-hJ[e] * INV_WS, hJ[e], hJJ[e]);
            float prod = Ivar * Jvar;
            float num  = cross * cross;
            if (!(prod > EPS)) { prod = 1.0f; num = 1.0f; }
            float inv_;
            asm("v_rcp_f32 %0, %1" : "=v"(inv_) : "v"(prod + EPS));
            accum += num * inv_;
        }
    }
#undef LD12

    // ---- wave reduction + one atomic per wave ----
    #pragma unroll
    for (int off = 32; off > 0; off >>= 1)
        accum += __shfl_xor(accum, off, 64);
    if (lane == 0) atomicAdd(&acc[b], accum);
}

__global__ void finalize_kernel(const float* __restrict__ acc, float* __restrict__ out) {
    if (threadIdx.x < BATCH)
        out[threadIdx.x] = 1.0f - acc[threadIdx.x] * (1.0f / (float)(H * W));
}

extern "C" void kernel_launch(void* const* d_in, const int* in_sizes, int n_in,
                              void* d_out, int out_size, void* d_ws, size_t ws_size,
                              hipStream_t stream) {
    const float* I = (const float*)d_in[0];
    const float* J = (const float*)d_in[1];
    float* out = (float*)d_out;
    float* acc = (float*)d_ws;

    zero_acc_kernel<<<1, 64, 0, stream>>>(acc);

    dim3 grid(BLOCKS_PER_IMG, BATCH);   // 96 x 16 = 1536 blocks, 4608 waves
    lncc4<<<grid, NTHREADS, 0, stream>>>(I, J, acc);

    finalize_kernel<<<1, 64, 0, stream>>>(acc, out);
}

// Round 8
// 61.950 us; speedup vs baseline: 2.9923x; 1.3984x over previous
//
#include <hip/hip_runtime.h>

// LNCC loss: I,J [16,1,768,768] f32 -> out [16] f32
// Thread-autonomous: each thread owns 4 output columns, redundantly computes
// the 12 colsums it needs (4 own + 4 halo each side). No LDS/shuffles/barriers.
// R7 post-mortem: loop was issue-12-loads -> wait -> compute, ~900cy cold-row
// latency exposed per row (VALUBusy 25%). R8 = R5 config (SEG=16, 65us) +
// software-pipelined loads (T14): next row's 12 loads issued before this
// row's compute, two named register sets P/Q (static indexing, rule #20).

constexpr int BATCH = 16;
constexpr int H = 768;
constexpr int W = 768;
constexpr float INV_WS = 1.0f / 81.0f;
constexpr float EPS = 3.0590232050182579e-07f;   // exp(-15)

constexpr int COLS = 4;                    // output cols per thread
constexpr int STRIPW = 64 * COLS;          // 256 cols per wave
constexpr int NSTRIP = W / STRIPW;         // 3
constexpr int SEG = 16;                    // output rows per wave task
constexpr int NSEG = H / SEG;              // 48
constexpr int WPB = 3;                     // waves per block
constexpr int NTHREADS = WPB * 64;         // 192
constexpr int BLOCKS_PER_IMG = (NSTRIP * NSEG) / WPB;   // 48

__global__ void zero_acc_kernel(float* acc) {
    if (threadIdx.x < BATCH) acc[threadIdx.x] = 0.0f;
}

__launch_bounds__(NTHREADS, 2)
__global__ void lncc4p(const float* __restrict__ gI, const float* __restrict__ gJ,
                       float* __restrict__ acc)
{
    const int lane  = threadIdx.x & 63;
    const int wv    = blockIdx.x * WPB + (threadIdx.x >> 6);
    const int b     = blockIdx.y;
    const int strip = wv % NSTRIP;
    const int seg   = wv / NSTRIP;
    const int r0    = seg * SEG;
    const int cbase = strip * STRIPW + lane * COLS;           // first owned col

    // three 16B-aligned 4-col chunks: [cbase-4], [cbase], [cbase+4]
    const float m0 = (cbase - 4 >= 0) ? 1.0f : 0.0f;   // left image edge
    const float m2 = (cbase + 8 <= W) ? 1.0f : 0.0f;   // right image edge
    const int ca0 = max(cbase - 4, 0);
    const int ca1 = cbase;
    const int ca2 = min(cbase + 4, W - 4);

    const float* __restrict__ Ib = gI + (size_t)b * (H * W);
    const float* __restrict__ Jb = gJ + (size_t)b * (H * W);

    // 8-row partial colsums of the 5 channels for the 12 columns.
    float cs0[12], cs1[12], cs2[12], cs3[12], cs4[12];
    #pragma unroll
    for (int x = 0; x < 12; ++x) {
        cs0[x] = 0.f; cs1[x] = 0.f; cs2[x] = 0.f; cs3[x] = 0.f; cs4[x] = 0.f;
    }

// 12 masked floats from one row (3 aligned float4 loads) — warm-up only
#define LD12(dst, base, roff, rm)                                         \
    {                                                                     \
        const float4 q0 = *(const float4*)((base) + (roff) + ca0);        \
        const float4 q1 = *(const float4*)((base) + (roff) + ca1);        \
        const float4 q2 = *(const float4*)((base) + (roff) + ca2);        \
        const float f0 = (rm) * m0, f1 = (rm), f2 = (rm) * m2;            \
        dst[0] = q0.x * f0; dst[1] = q0.y * f0;                           \
        dst[2] = q0.z * f0; dst[3] = q0.w * f0;                           \
        dst[4] = q1.x * f1; dst[5] = q1.y * f1;                           \
        dst[6] = q1.z * f1; dst[7] = q1.w * f1;                           \
        dst[8] = q2.x * f2; dst[9] = q2.y * f2;                           \
        dst[10] = q2.z * f2; dst[11] = q2.w * f2;                         \
    }

    // ---- warm-up: rows r0-4 .. r0+3 (zero above the image) ----
    #pragma unroll
    for (int k = 0; k < 8; ++k) {
        const int r = r0 - 4 + k;
        const float rm = (r >= 0) ? 1.0f : 0.0f;
        const int roff = max(r, 0) * W;
        float vi[12], vj[12];
        LD12(vi, Ib, roff, rm)
        LD12(vj, Jb, roff, rm)
        #pragma unroll
        for (int x = 0; x < 12; ++x) {
            cs0[x] += vi[x];
            cs1[x] += vj[x];
            cs2[x] = fmaf(vi[x], vi[x], cs2[x]);
            cs3[x] = fmaf(vj[x], vj[x], cs3[x]);
            cs4[x] = fmaf(vi[x], vj[x], cs4[x]);
        }
    }
#undef LD12

    float accum = 0.0f;

    // ---- prefetch register sets (named float4s; static only) ----
    float4 Pvi0, Pvi1, Pvi2, Pvj0, Pvj1, Pvj2, Poi0, Poi1, Poi2, Poj0, Poj1, Poj2;
    float4 Qvi0, Qvi1, Qvi2, Qvj0, Qvj1, Qvj2, Qoi0, Qoi1, Qoi2, Qoj0, Qoj1, Qoj2;

// issue 12 raw float4 loads for output row rr (addresses clamped; mask at consume)
#define ISSUE(S, rr)                                                      \
    {                                                                     \
        const int rin_  = min((rr) + 4, H - 1);                           \
        const int rout_ = max((rr) - 4, 0);                               \
        const float* piI = Ib + rin_  * W;                                \
        const float* poI = Ib + rout_ * W;                                \
        const float* piJ = Jb + rin_  * W;                                \
        const float* poJ = Jb + rout_ * W;                                \
        S##vi0 = *(const float4*)(piI + ca0);                             \
        S##vi1 = *(const float4*)(piI + ca1);                             \
        S##vi2 = *(const float4*)(piI + ca2);                             \
        S##vj0 = *(const float4*)(piJ + ca0);                             \
        S##vj1 = *(const float4*)(piJ + ca1);                             \
        S##vj2 = *(const float4*)(piJ + ca2);                             \
        S##oi0 = *(const float4*)(poI + ca0);                             \
        S##oi1 = *(const float4*)(poI + ca1);                             \
        S##oi2 = *(const float4*)(poI + ca2);                             \
        S##oj0 = *(const float4*)(poJ + ca0);                             \
        S##oj1 = *(const float4*)(poJ + ca1);                             \
        S##oj2 = *(const float4*)(poJ + ca2);                             \
    }

#define UNPACK(dst, s0, s1, s2, rm)                                       \
    {                                                                     \
        const float f0 = (rm) * m0, f1 = (rm), f2 = (rm) * m2;            \
        dst[0] = s0.x * f0; dst[1] = s0.y * f0;                           \
        dst[2] = s0.z * f0; dst[3] = s0.w * f0;                           \
        dst[4] = s1.x * f1; dst[5] = s1.y * f1;                           \
        dst[6] = s1.z * f1; dst[7] = s1.w * f1;                           \
        dst[8] = s2.x * f2; dst[9] = s2.y * f2;                           \
        dst[10] = s2.z * f2; dst[11] = s2.w * f2;                         \
    }

#define HSUM(T, h)                                                        \
    {                                                                     \
        float s_ = T[0] + T[1] + T[2] + T[3] + T[4] + T[5] + T[6]         \
                 + T[7] + T[8];                                           \
        h[0] = s_;                                                        \
        s_ += T[9]  - T[0]; h[1] = s_;                                    \
        s_ += T[10] - T[1]; h[2] = s_;                                    \
        s_ += T[11] - T[2]; h[3] = s_;                                    \
    }

// consume prefetch set S for output row rr: mask, colsum update, hsum, math
#define CONSUME(S, rr)                                                    \
    {                                                                     \
        const float rmi = ((rr) + 4 < H)  ? 1.0f : 0.0f;                  \
        const float rmo = ((rr) - 4 >= 0) ? 1.0f : 0.0f;                  \
        float vi[12], vj[12], oi[12], oj[12];                             \
        UNPACK(vi, S##vi0, S##vi1, S##vi2, rmi)                           \
        UNPACK(vj, S##vj0, S##vj1, S##vj2, rmi)                           \
        UNPACK(oi, S##oi0, S##oi1, S##oi2, rmo)                           \
        UNPACK(oj, S##oj0, S##oj1, S##oj2, rmo)                           \
        float t0[12], t1[12], t2[12], t3[12], t4[12];                     \
        _Pragma("unroll")                                                 \
        for (int x = 0; x < 12; ++x) {                                    \
            t0[x] = cs0[x] + vi[x];                                       \
            t1[x] = cs1[x] + vj[x];                                       \
            t2[x] = fmaf(vi[x], vi[x], cs2[x]);                           \
            t3[x] = fmaf(vj[x], vj[x], cs3[x]);                           \
            t4[x] = fmaf(vi[x], vj[x], cs4[x]);                           \
            cs0[x] = t0[x] - oi[x];                                       \
            cs1[x] = t1[x] - oj[x];                                       \
            cs2[x] = fmaf(oi[x], -oi[x], t2[x]);                          \
            cs3[x] = fmaf(oj[x], -oj[x], t3[x]);                          \
            cs4[x] = fmaf(oi[x], -oj[x], t4[x]);                          \
        }                                                                 \
        float hI[4], hJ[4], hII[4], hJJ[4], hIJ[4];                       \
        HSUM(t0, hI)                                                      \
        HSUM(t1, hJ)                                                      \
        HSUM(t2, hII)                                                     \
        HSUM(t3, hJJ)                                                     \
        HSUM(t4, hIJ)                                                     \
        _Pragma("unroll")                                                 \
        for (int e = 0; e < 4; ++e) {                                     \
            const float u = -hI[e] * INV_WS;                              \
            const float cross = fmaf(u, hJ[e], hIJ[e]);                   \
            const float Ivar  = fmaf(u, hI[e], hII[e]);                   \
            const float Jvar  = fmaf(-hJ[e] * INV_WS, hJ[e], hJJ[e]);     \
            float prod = Ivar * Jvar;                                     \
            float num  = cross * cross;                                   \
            if (!(prod > EPS)) { prod = 1.0f; num = 1.0f; }               \
            float inv_;                                                   \
            asm("v_rcp_f32 %0, %1" : "=v"(inv_) : "v"(prod + EPS));       \
            accum += num * inv_;                                          \
        }                                                                 \
    }

    // ---- software-pipelined main loop: 2 rows per iteration ----
    ISSUE(P, r0)
    #pragma unroll 1
    for (int r = r0; r < r0 + SEG; r += 2) {
        ISSUE(Q, r + 1)          // row r+1 loads fly during row r compute
        CONSUME(P, r)
        ISSUE(P, r + 2)          // row r+2 loads fly during row r+1 compute
        CONSUME(Q, r + 1)
    }
#undef ISSUE
#undef UNPACK
#undef HSUM
#undef CONSUME

    // ---- wave reduction + one atomic per wave ----
    #pragma unroll
    for (int off = 32; off > 0; off >>= 1)
        accum += __shfl_xor(accum, off, 64);
    if (lane == 0) atomicAdd(&acc[b], accum);
}

__global__ void finalize_kernel(const float* __restrict__ acc, float* __restrict__ out) {
    if (threadIdx.x < BATCH)
        out[threadIdx.x] = 1.0f - acc[threadIdx.x] * (1.0f / (float)(H * W));
}

extern "C" void kernel_launch(void* const* d_in, const int* in_sizes, int n_in,
                              void* d_out, int out_size, void* d_ws, size_t ws_size,
                              hipStream_t stream) {
    const float* I = (const float*)d_in[0];
    const float* J = (const float*)d_in[1];
    float* out = (float*)d_out;
    float* acc = (float*)d_ws;

    zero_acc_kernel<<<1, 64, 0, stream>>>(acc);

    dim3 grid(BLOCKS_PER_IMG, BATCH);   // 48 x 16 = 768 blocks, 2304 waves
    lncc4p<<<grid, NTHREADS, 0, stream>>>(I, J, acc);

    finalize_kernel<<<1, 64, 0, stream>>>(acc, out);
}

// Round 9
// 57.119 us; speedup vs baseline: 3.2453x; 1.0846x over previous
//
#include <hip/hip_runtime.h>

// LNCC loss: I,J [16,1,768,768] f32 -> out [16] f32
// Full-width block (3 waves, 4 cols/thread) + 10-slot LDS row ring.
// Per row each thread loads ONLY its own 16B chunk per image (2 VMEM vs 12 in
// R5-R8: kills the 3x inter-lane redundancy AND the out-row global reload that
// was thrashing L1). Halos + out-row come from LDS; rows pre-scaled by the
// boundary mask at staging so the consume path is branch-free. Staging is
// pipelined one row ahead (P/Q regs); one barrier per row.

constexpr int BATCH = 16;
constexpr int H = 768;
constexpr int W = 768;
constexpr float INV_WS = 1.0f / 81.0f;
constexpr float EPS = 3.0590232050182579e-07f;   // exp(-15)

constexpr int SEG = 24;                   // output rows per block
constexpr int NSEG = H / SEG;             // 32
constexpr int NTHREADS = 192;             // 3 waves; 192*4 = 768 cols
constexpr int RING = 10;                  // row slots (9-window + 1 slack)
constexpr int PADL = 4;                   // zero pad cols each side
constexpr int LW = PADL + W + PADL;       // 776

__global__ void zero_acc_kernel(float* acc) {
    if (threadIdx.x < BATCH) acc[threadIdx.x] = 0.0f;
}

__launch_bounds__(NTHREADS, 2)
__global__ void lncc_ring(const float* __restrict__ gI, const float* __restrict__ gJ,
                          float* __restrict__ acc)
{
    __shared__ float ring[RING][2][LW];   // 10*2*776*4 = 62080 B -> 2 blocks/CU

    const int t    = threadIdx.x;
    const int lane = t & 63;
    const int seg  = blockIdx.x;
    const int b    = blockIdx.y;
    const int r0   = seg * SEG;
    const int gc   = 4 * t;               // first owned global col

    const float* __restrict__ Ib = gI + (size_t)b * (H * W);
    const float* __restrict__ Jb = gJ + (size_t)b * (H * W);

    // zero the pad columns once (never written again)
    for (int i = t; i < RING * 2 * 8; i += NTHREADS) {
        const int slot = i >> 4;
        const int img  = (i >> 3) & 1;
        const int k    = i & 7;
        ring[slot][img][(k < 4) ? k : (LW - 8 + k)] = 0.f;
    }

    float cs0[12], cs1[12], cs2[12], cs3[12], cs4[12];
    #pragma unroll
    for (int x = 0; x < 12; ++x) { cs0[x]=cs1[x]=cs2[x]=cs3[x]=cs4[x]=0.f; }

    // ---- warm-up staging: rows r0-4 .. r0+3 (pre-scaled by row mask) ----
    #pragma unroll
    for (int k = 0; k < 8; ++k) {
        const int rr = r0 - 4 + k;                   // <= 747, never >= H
        const int rc = max(rr, 0);
        const float rm = (rr >= 0) ? 1.0f : 0.0f;
        const float4 qi = *(const float4*)(Ib + (size_t)rc * W + gc);
        const float4 qj = *(const float4*)(Jb + (size_t)rc * W + gc);
        const int s = (rr + RING) % RING;
        *(float4*)&ring[s][0][PADL + gc] = make_float4(qi.x*rm, qi.y*rm, qi.z*rm, qi.w*rm);
        *(float4*)&ring[s][1][PADL + gc] = make_float4(qj.x*rm, qj.y*rm, qj.z*rm, qj.w*rm);
    }
    // prefetch row r0+4 into pipeline regs P
    float4 Pi, Pj; float Prm;
    {
        const int rr = r0 + 4;
        const int rc = min(rr, H - 1);
        Prm = (rr < H) ? 1.0f : 0.0f;
        Pi = *(const float4*)(Ib + (size_t)rc * W + gc);
        Pj = *(const float4*)(Jb + (size_t)rc * W + gc);
    }
    __syncthreads();

    // ---- warm-up accumulate: 8 rows, 12 cols each, all from LDS ----
    #pragma unroll
    for (int k = 0; k < 8; ++k) {
        const int s = (r0 - 4 + k + RING) % RING;
        const float4* pI = (const float4*)&ring[s][0][4 * t];   // cols gc-4..gc+7
        const float4* pJ = (const float4*)&ring[s][1][4 * t];
        const float4 a0 = pI[0], a1 = pI[1], a2 = pI[2];
        const float4 c0 = pJ[0], c1 = pJ[1], c2 = pJ[2];
        const float vi[12] = {a0.x,a0.y,a0.z,a0.w, a1.x,a1.y,a1.z,a1.w, a2.x,a2.y,a2.z,a2.w};
        const float vj[12] = {c0.x,c0.y,c0.z,c0.w, c1.x,c1.y,c1.z,c1.w, c2.x,c2.y,c2.z,c2.w};
        #pragma unroll
        for (int x = 0; x < 12; ++x) {
            cs0[x] += vi[x];
            cs1[x] += vj[x];
            cs2[x] = fmaf(vi[x], vi[x], cs2[x]);
            cs3[x] = fmaf(vj[x], vj[x], cs3[x]);
            cs4[x] = fmaf(vi[x], vj[x], cs4[x]);
        }
    }

#define HSUM(T, h)                                                        \
    {                                                                     \
        float s_ = T[0] + T[1] + T[2] + T[3] + T[4] + T[5] + T[6]         \
                 + T[7] + T[8];                                           \
        h[0] = s_;                                                        \
        s_ += T[9]  - T[0]; h[1] = s_;                                    \
        s_ += T[10] - T[1]; h[2] = s_;                                    \
        s_ += T[11] - T[2]; h[3] = s_;                                    \
    }

    float accum = 0.0f;

    // ---- main loop: one output row per iteration, one barrier per row ----
    #pragma unroll 1
    for (int r = r0; r < r0 + SEG; ++r) {
        // issue next-next row's loads (row r+5) while everything else runs
        float4 Qi, Qj; float Qrm;
        {
            const int rq = r + 5;
            const int rc = min(rq, H - 1);
            Qrm = (rq < H) ? 1.0f : 0.0f;
            Qi = *(const float4*)(Ib + (size_t)rc * W + gc);
            Qj = *(const float4*)(Jb + (size_t)rc * W + gc);
        }
        // stage row r+4 (loaded last iteration), pre-scaled
        const int sw = (r + 4) % RING;
        const float4 wi = make_float4(Pi.x*Prm, Pi.y*Prm, Pi.z*Prm, Pi.w*Prm);
        const float4 wj = make_float4(Pj.x*Prm, Pj.y*Prm, Pj.z*Prm, Pj.w*Prm);
        *(float4*)&ring[sw][0][PADL + gc] = wi;
        *(float4*)&ring[sw][1][PADL + gc] = wj;
        __syncthreads();

        // in-add: own chunk from regs, halo chunks from LDS
        {
            const float4 iL = *(const float4*)&ring[sw][0][4 * t];
            const float4 iR = *(const float4*)&ring[sw][0][4 * t + 8];
            const float4 jL = *(const float4*)&ring[sw][1][4 * t];
            const float4 jR = *(const float4*)&ring[sw][1][4 * t + 8];
            const float vi[12] = {iL.x,iL.y,iL.z,iL.w, wi.x,wi.y,wi.z,wi.w, iR.x,iR.y,iR.z,iR.w};
            const float vj[12] = {jL.x,jL.y,jL.z,jL.w, wj.x,wj.y,wj.z,wj.w, jR.x,jR.y,jR.z,jR.w};
            #pragma unroll
            for (int x = 0; x < 12; ++x) {
                cs0[x] += vi[x];
                cs1[x] += vj[x];
                cs2[x] = fmaf(vi[x], vi[x], cs2[x]);
                cs3[x] = fmaf(vj[x], vj[x], cs3[x]);
                cs4[x] = fmaf(vi[x], vj[x], cs4[x]);
            }
        }

        // cs now holds the 9-row colsums: horizontal 9-sums + pixel math
        {
            float hI[4], hJ[4], hII[4], hJJ[4], hIJ[4];
            HSUM(cs0, hI)
            HSUM(cs1, hJ)
            HSUM(cs2, hII)
            HSUM(cs3, hJJ)
            HSUM(cs4, hIJ)
            #pragma unroll
            for (int e = 0; e < 4; ++e) {
                const float u = -hI[e] * INV_WS;
                const float cross = fmaf(u, hJ[e], hIJ[e]);
                const float Ivar  = fmaf(u, hI[e], hII[e]);
                const float Jvar  = fmaf(-hJ[e] * INV_WS, hJ[e], hJJ[e]);
                float prod = Ivar * Jvar;
                float num  = cross * cross;
                if (!(prod > EPS)) { prod = 1.0f; num = 1.0f; }
                float inv_;
                asm("v_rcp_f32 %0, %1" : "=v"(inv_) : "v"(prod + EPS));
                accum += num * inv_;
            }
        }

        // out-sub: row r-4 from the ring (no global reload)
        {
            const int so = (r - 4 + RING) % RING;
            const float4* pI = (const float4*)&ring[so][0][4 * t];
            const float4* pJ = (const float4*)&ring[so][1][4 * t];
            const float4 a0 = pI[0], a1 = pI[1], a2 = pI[2];
            const float4 c0 = pJ[0], c1 = pJ[1], c2 = pJ[2];
            const float oi[12] = {a0.x,a0.y,a0.z,a0.w, a1.x,a1.y,a1.z,a1.w, a2.x,a2.y,a2.z,a2.w};
            const float oj[12] = {c0.x,c0.y,c0.z,c0.w, c1.x,c1.y,c1.z,c1.w, c2.x,c2.y,c2.z,c2.w};
            #pragma unroll
            for (int x = 0; x < 12; ++x) {
                cs0[x] -= oi[x];
                cs1[x] -= oj[x];
                cs2[x] = fmaf(oi[x], -oi[x], cs2[x]);
                cs3[x] = fmaf(oj[x], -oj[x], cs3[x]);
                cs4[x] = fmaf(oi[x], -oj[x], cs4[x]);
            }
        }

        Pi = Qi; Pj = Qj; Prm = Qrm;
    }
#undef HSUM

    // ---- wave reduction + one atomic per wave ----
    #pragma unroll
    for (int off = 32; off > 0; off >>= 1)
        accum += __shfl_xor(accum, off, 64);
    if (lane == 0) atomicAdd(&acc[b], accum);
}

__global__ void finalize_kernel(const float* __restrict__ acc, float* __restrict__ out) {
    if (threadIdx.x < BATCH)
        out[threadIdx.x] = 1.0f - acc[threadIdx.x] * (1.0f / (float)(H * W));
}

extern "C" void kernel_launch(void* const* d_in, const int* in_sizes, int n_in,
                              void* d_out, int out_size, void* d_ws, size_t ws_size,
                              hipStream_t stream) {
    const float* I = (const float*)d_in[0];
    const float* J = (const float*)d_in[1];
    float* out = (float*)d_out;
    float* acc = (float*)d_ws;

    zero_acc_kernel<<<1, 64, 0, stream>>>(acc);

    dim3 grid(NSEG, BATCH);   // 32 x 16 = 512 blocks = exactly 2 resident/CU
    lncc_ring<<<grid, NTHREADS, 0, stream>>>(I, J, acc);

    finalize_kernel<<<1, 64, 0, stream>>>(acc, out);
}